// Round 3
// baseline (186.290 us; speedup 1.0000x reference)
//
#include <hip/hip_runtime.h>

typedef __bf16 bf16;
typedef __bf16 bf16x4 __attribute__((ext_vector_type(4)));
typedef __bf16 bf16x8 __attribute__((ext_vector_type(8)));
typedef float  f32x4  __attribute__((ext_vector_type(4)));

#define T_DIM 256
#define B_DIM 256
#define NIN   512
#define NH    512
#define NEMB  256
#define NX    768      // NIN + NEMB
#define NG    1536     // 3*NH

__device__ __forceinline__ float fast_tanh(float x) {
    float e = __expf(2.0f * x);
    return 1.0f - 2.0f * __builtin_amdgcn_rcpf(e + 1.0f);
}
__device__ __forceinline__ float fast_sigmoid(float x) {
    return __builtin_amdgcn_rcpf(1.0f + __expf(-x));
}

__device__ __forceinline__ void gload_lds16(const bf16* g, bf16* l) {
    __builtin_amdgcn_global_load_lds(
        (const __attribute__((address_space(1))) void*)g,
        (__attribute__((address_space(3))) void*)l, 16, 0, 0);
}

// ---------------- fused weight/h conversion (5 segments, grid-stride) ----------------
__global__ __launch_bounds__(256) void cvt_weights(
    const float* __restrict__ a0, const float* __restrict__ a1,
    const float* __restrict__ a2, const float* __restrict__ a3,
    const float* __restrict__ a4,
    bf16* __restrict__ b0, bf16* __restrict__ b1, bf16* __restrict__ b2,
    bf16* __restrict__ b3, bf16* __restrict__ b4) {
    const int N0 = 65536, N1 = 131072, N2 = 425984, N3 = 622592, N4 = 655360;
    for (int i = blockIdx.x * 256 + threadIdx.x; i < N4; i += gridDim.x * 256) {
        const float* s; bf16* d; int j;
        if (i < N0)      { s = a0; d = b0; j = i; }
        else if (i < N1) { s = a1; d = b1; j = i - N0; }
        else if (i < N2) { s = a2; d = b2; j = i - N1; }
        else if (i < N3) { s = a3; d = b3; j = i - N2; }
        else             { s = a4; d = b4; j = i - N3; }
        float4 v = reinterpret_cast<const float4*>(s)[j];
        bf16x4 o = { (bf16)v.x, (bf16)v.y, (bf16)v.z, (bf16)v.w };
        reinterpret_cast<bf16x4*>(d)[j] = o;
    }
}

// ---------------- feats f32 -> bf16, pre-swizzled rows ----------------
// featsb[m][c ^ ((m&7)<<3)] = feats[m][c]   (XOR on element idx bits 3..5)
__global__ __launch_bounds__(256) void cvt_feats(
    const float* __restrict__ f, bf16* __restrict__ fb) {
    const int total = 65536 * 64;   // 8-elem groups
    for (int idx = blockIdx.x * 256 + threadIdx.x; idx < total; idx += gridDim.x * 256) {
        int m = idx >> 6, c8 = idx & 63;
        const float* src = f + ((size_t)m * 512 + c8 * 8);
        float4 v0 = *reinterpret_cast<const float4*>(src);
        float4 v1 = *reinterpret_cast<const float4*>(src + 4);
        bf16x8 o = { (bf16)v0.x, (bf16)v0.y, (bf16)v0.z, (bf16)v0.w,
                     (bf16)v1.x, (bf16)v1.y, (bf16)v1.z, (bf16)v1.w };
        int g = c8 ^ (m & 7);
        reinterpret_cast<bf16x8*>(fb)[(size_t)m * 64 + g] = o;
    }
}

// ---------------- generic GEMM: C[M,N] = A[M,K] * B[N,K]^T + bias[N] ----------------
__global__ __launch_bounds__(256) void gemm_bias(
    const bf16* __restrict__ A, const bf16* __restrict__ B,
    const float* __restrict__ bias, float* __restrict__ C,
    int M, int N, int K) {
    __shared__ bf16 At[64][40];
    __shared__ bf16 Bt[64][40];
    const int tid = threadIdx.x;
    const int m0 = blockIdx.y * 64, n0 = blockIdx.x * 64;
    const int wid = tid >> 6, lane = tid & 63, hi = lane >> 4, lo = lane & 15;
    const int srow = tid >> 2, sseg = tid & 3;
    f32x4 acc[4] = {};

    for (int kk = 0; kk < K; kk += 32) {
        bf16x8 av = *reinterpret_cast<const bf16x8*>(A + (size_t)(m0 + srow) * K + kk + sseg * 8);
        bf16x8 bv = *reinterpret_cast<const bf16x8*>(B + (size_t)(n0 + srow) * K + kk + sseg * 8);
        __syncthreads();
        *reinterpret_cast<bf16x8*>(&At[srow][sseg * 8]) = av;
        *reinterpret_cast<bf16x8*>(&Bt[srow][sseg * 8]) = bv;
        __syncthreads();
        bf16x8 a = *reinterpret_cast<const bf16x8*>(&At[wid * 16 + lo][hi * 8]);
#pragma unroll
        for (int nt = 0; nt < 4; ++nt) {
            bf16x8 b = *reinterpret_cast<const bf16x8*>(&Bt[nt * 16 + lo][hi * 8]);
            acc[nt] = __builtin_amdgcn_mfma_f32_16x16x32_bf16(a, b, acc[nt], 0, 0, 0);
        }
    }
#pragma unroll
    for (int nt = 0; nt < 4; ++nt) {
        int n = n0 + nt * 16 + lo;
        float bv = bias[n];
#pragma unroll
        for (int r = 0; r < 4; ++r) {
            int m = m0 + wid * 16 + hi * 4 + r;
            C[(size_t)m * N + n] = acc[nt][r] + bv;
        }
    }
}

// ---------------- fused emit kernel (v2: global_load_lds staging) ----------------
__global__ __launch_bounds__(512, 4) void emit_kernel(
    const bf16* __restrict__ featsb, const bf16* __restrict__ W,
    const float* __restrict__ hbuf, const float* __restrict__ wscore,
    float* __restrict__ emit_out) {
    __shared__ bf16 Atile[64 * 512];   // 64KB, content = pre-swizzled rows
    const int tid = threadIdx.x;
    const int m0 = blockIdx.x * 64;
    const int wid = tid >> 6, lane = tid & 63, hi = lane >> 4, lo = lane & 15;

    // async DMA staging: 8 rounds x (8 waves x 1KB); source is pre-swizzled -> linear dest OK
    const bf16* gs = featsb + (size_t)m0 * 512;
#pragma unroll
    for (int r = 0; r < 8; ++r)
        gload_lds16(gs + r * 4096 + wid * 512 + lane * 8,
                    Atile + r * 4096 + wid * 512);
    __syncthreads();   // compiler emits vmcnt(0) before barrier

    const int n0 = wid * 64;
    f32x4 acc[4][4] = {};   // [nt][st]

    for (int kk = 0; kk < 16; ++kk) {
        bf16x8 a[4];
#pragma unroll
        for (int st = 0; st < 4; ++st) {
            int row = st * 16 + lo;
            int el = row * 512 + (((kk * 32) + hi * 8) ^ ((row & 7) << 3));
            a[st] = *reinterpret_cast<const bf16x8*>(Atile + el);
        }
#pragma unroll
        for (int nt = 0; nt < 4; ++nt) {
            bf16x8 b = *reinterpret_cast<const bf16x8*>(
                W + (size_t)(n0 + nt * 16 + lo) * NIN + kk * 32 + hi * 8);
#pragma unroll
            for (int st = 0; st < 4; ++st)
                acc[nt][st] = __builtin_amdgcn_mfma_f32_16x16x32_bf16(a[st], b, acc[nt][st], 0, 0, 0);
        }
    }

    // epilogue: add h_, tanh, dot with w_score — in registers
    float ep[4][4] = {};
    const int bbase = m0 & (B_DIM - 1);
#pragma unroll
    for (int nt = 0; nt < 4; ++nt) {
        int n = n0 + nt * 16 + lo;
        float wsn = wscore[n];
#pragma unroll
        for (int st = 0; st < 4; ++st) {
#pragma unroll
            for (int r = 0; r < 4; ++r) {
                int b = bbase + st * 16 + hi * 4 + r;
                float x = acc[nt][st][r] + hbuf[(size_t)b * NH + n];
                ep[st][r] += fast_tanh(x) * wsn;
            }
        }
    }
#pragma unroll
    for (int st = 0; st < 4; ++st)
#pragma unroll
        for (int r = 0; r < 4; ++r)
#pragma unroll
            for (int off = 1; off < 16; off <<= 1)
                ep[st][r] += __shfl_xor(ep[st][r], off, 64);

    __syncthreads();
    float* ew = reinterpret_cast<float*>(Atile);   // alias, safe after barrier
    if (lo == 0) {
#pragma unroll
        for (int st = 0; st < 4; ++st)
#pragma unroll
            for (int r = 0; r < 4; ++r)
                ew[wid * 64 + st * 16 + hi * 4 + r] = ep[st][r];
    }
    __syncthreads();
    if (tid < 64) {
        float s = 0.0f;
#pragma unroll
        for (int ww = 0; ww < 8; ++ww) s += ew[ww * 64 + tid];
        emit_out[m0 + tid] = s;
    }
}

// ---------------- softmax over T (per column b) ----------------
__global__ __launch_bounds__(256) void softmax_t(
    const float* __restrict__ emit, float* __restrict__ alpha, float* __restrict__ out_alpha) {
    int b = blockIdx.x, t = threadIdx.x;
    int wv = t >> 6, ln = t & 63;
    float e = emit[(size_t)t * B_DIM + b];
    float m = e;
#pragma unroll
    for (int off = 32; off; off >>= 1) m = fmaxf(m, __shfl_xor(m, off, 64));
    __shared__ float red[4], red2[4];
    if (ln == 0) red[wv] = m;
    __syncthreads();
    m = fmaxf(fmaxf(red[0], red[1]), fmaxf(red[2], red[3]));
    float p = __expf(e - m);
    float s = p;
#pragma unroll
    for (int off = 32; off; off >>= 1) s += __shfl_xor(s, off, 64);
    if (ln == 0) red2[wv] = s;
    __syncthreads();
    float inv = __builtin_amdgcn_rcpf(red2[0] + red2[1] + red2[2] + red2[3]);
    float a = p * inv;
    alpha[(size_t)t * B_DIM + b] = a;
    out_alpha[(size_t)t * B_DIM + b] = a;
}

// ---------------- context + build_x fused ----------------
// x[b][0..511] = (bf16) sum_t alpha[t,b]*feats[t,b,c];  x[b][512..767] = (bf16) emb
__global__ __launch_bounds__(256) void ctx_kernel(
    const bf16* __restrict__ featsb, const float* __restrict__ alpha,
    const float* __restrict__ emb, bf16* __restrict__ x) {
    int b = blockIdx.x;
    __shared__ float al[T_DIM];
    __shared__ float red[4][512];
    int tid = threadIdx.x;
    al[tid] = alpha[(size_t)tid * B_DIM + b];
    __syncthreads();
    int c8 = tid & 63, tq = tid >> 6;
    int g = c8 ^ (b & 7);   // inverse of the row swizzle (m&7 == b&7 since B%8==0)
    float acc[8] = {};
    for (int t = tq * 64; t < tq * 64 + 64; ++t) {
        bf16x8 v = reinterpret_cast<const bf16x8*>(featsb)[((size_t)t * B_DIM + b) * 64 + g];
        float a = al[t];
#pragma unroll
        for (int j = 0; j < 8; ++j) acc[j] += a * (float)v[j];
    }
#pragma unroll
    for (int j = 0; j < 8; ++j) red[tq][c8 * 8 + j] = acc[j];
    __syncthreads();
#pragma unroll
    for (int k = 0; k < 2; ++k) {
        int c = tid * 2 + k;
        float s = red[0][c] + red[1][c] + red[2][c] + red[3][c];
        x[(size_t)b * NX + c] = (bf16)s;
    }
    x[(size_t)b * NX + NIN + tid] = (bf16)emb[(size_t)b * NEMB + tid];
}

// ---------------- GRU gates ----------------
__global__ __launch_bounds__(256) void gru_kernel(
    const float* __restrict__ gi, const float* __restrict__ gh,
    const float* __restrict__ h, float* __restrict__ out) {
    int idx = blockIdx.x * 256 + threadIdx.x;
    int b = idx >> 9, j = idx & 511;
    const float* gib = gi + (size_t)b * NG;
    const float* ghb = gh + (size_t)b * NG;
    float r = fast_sigmoid(gib[j] + ghb[j]);
    float z = fast_sigmoid(gib[NH + j] + ghb[NH + j]);
    float n = fast_tanh(gib[2 * NH + j] + r * ghb[2 * NH + j]);
    out[idx] = (1.0f - z) * n + z * h[idx];
}

extern "C" void kernel_launch(void* const* d_in, const int* in_sizes, int n_in,
                              void* d_out, int out_size, void* d_ws, size_t ws_size,
                              hipStream_t stream) {
    const float* feats = (const float*)d_in[0];
    const float* h     = (const float*)d_in[1];
    const float* emb   = (const float*)d_in[2];
    const float* w_i2h = (const float*)d_in[3];
    const float* w_h2h = (const float*)d_in[4];
    const float* b_h2h = (const float*)d_in[5];
    const float* w_sc  = (const float*)d_in[6];
    const float* w_ih  = (const float*)d_in[7];
    const float* w_hh  = (const float*)d_in[8];
    const float* b_ih  = (const float*)d_in[9];
    const float* b_hh  = (const float*)d_in[10];
    float* out = (float*)d_out;

    char* ws = (char*)d_ws;
    bf16*  w_i2h_b = (bf16*)(ws);                 // 524288
    bf16*  w_h2h_b = (bf16*)(ws + 524288);        // 524288
    bf16*  w_ih_b  = (bf16*)(ws + 1048576);       // 2359296
    bf16*  w_hh_b  = (bf16*)(ws + 3407872);       // 1572864
    bf16*  h_b     = (bf16*)(ws + 4980736);       // 262144
    bf16*  x_b     = (bf16*)(ws + 5242880);       // 393216
    float* hbuf    = (float*)(ws + 5636096);      // 524288
    float* emit    = (float*)(ws + 6160384);      // 262144
    float* alpha   = (float*)(ws + 6422528);      // 262144
    float* gi      = (float*)(ws + 6684672);      // 1572864
    float* gh      = (float*)(ws + 8257536);      // 1572864
    bf16*  featsb  = (bf16*)(ws + 9830400);       // 67108864  -> total 76939264

    // 1) conversions
    cvt_weights<<<1024, 256, 0, stream>>>(w_i2h, w_h2h, w_ih, w_hh, h,
                                          w_i2h_b, w_h2h_b, w_ih_b, w_hh_b, h_b);
    cvt_feats<<<2048, 256, 0, stream>>>(feats, featsb);

    // 2) h_ = h @ w_h2h^T + b_h2h
    gemm_bias<<<dim3(8, 4), 256, 0, stream>>>(h_b, w_h2h_b, b_h2h, hbuf, 256, NH, NH);

    // 3) fused emit
    emit_kernel<<<1024, 512, 0, stream>>>(featsb, w_i2h_b, hbuf, w_sc, emit);

    // 4) alpha = softmax_T(emit); also output 1
    softmax_t<<<256, 256, 0, stream>>>(emit, alpha, out + 131072);

    // 5) context + x build (fused)
    ctx_kernel<<<256, 256, 0, stream>>>(featsb, alpha, emb, x_b);

    // 6) gi / gh GEMMs
    gemm_bias<<<dim3(24, 4), 256, 0, stream>>>(x_b, w_ih_b, b_ih, gi, 256, NG, NX);
    gemm_bias<<<dim3(24, 4), 256, 0, stream>>>(h_b, w_hh_b, b_hh, gh, 256, NG, NH);

    // 7) GRU -> nh (output 0)
    gru_kernel<<<512, 256, 0, stream>>>(gi, gh, h, out);
}

// Round 4
// 122.609 us; speedup vs baseline: 1.5194x; 1.5194x over previous
//
#include <hip/hip_runtime.h>

typedef __bf16 bf16;
typedef __bf16 bf16x4 __attribute__((ext_vector_type(4)));
typedef __bf16 bf16x8 __attribute__((ext_vector_type(8)));
typedef float  f32x4  __attribute__((ext_vector_type(4)));

#define T_DIM 256
#define B_DIM 256
#define NIN   512
#define NH    512
#define NEMB  256
#define NX    768      // NIN + NEMB
#define NG    1536     // 3*NH

__device__ __forceinline__ float fast_tanh(float x) {
    float e = __expf(2.0f * x);
    return 1.0f - 2.0f * __builtin_amdgcn_rcpf(e + 1.0f);
}
__device__ __forceinline__ float fast_sigmoid(float x) {
    return __builtin_amdgcn_rcpf(1.0f + __expf(-x));
}

__device__ __forceinline__ void gload_lds16(const bf16* g, bf16* l) {
    __builtin_amdgcn_global_load_lds(
        (const __attribute__((address_space(1))) void*)g,
        (__attribute__((address_space(3))) void*)l, 16, 0, 0);
}

// element-index XOR swizzle: spread k-bits 3..4 by row/col bits 1..2
__device__ __forceinline__ int swz(int rc) { return ((rc >> 1) & 3) << 3; }

// ---------------- weight/h conversion; w_i2h goes to swizzled K-step image ----------------
// Wimg[kk][col][k ^ swz(col)] = w_i2h[col][kk*32+k]   (kk<16, col<512, k<32)
__global__ __launch_bounds__(256) void cvt_weights(
    const float* __restrict__ a0, const float* __restrict__ a1,
    const float* __restrict__ a2, const float* __restrict__ a3,
    const float* __restrict__ a4,
    bf16* __restrict__ b0, bf16* __restrict__ b1, bf16* __restrict__ b2,
    bf16* __restrict__ b3, bf16* __restrict__ b4) {
    const int N0 = 65536, N1 = 131072, N2 = 425984, N3 = 622592, N4 = 655360;
    for (int i = blockIdx.x * 256 + threadIdx.x; i < N4; i += gridDim.x * 256) {
        const float* s; bf16* d; int j; bool img = false;
        if (i < N0)      { s = a0; d = b0; j = i; img = true; }
        else if (i < N1) { s = a1; d = b1; j = i - N0; }
        else if (i < N2) { s = a2; d = b2; j = i - N1; }
        else if (i < N3) { s = a3; d = b3; j = i - N2; }
        else             { s = a4; d = b4; j = i - N3; }
        float4 v = reinterpret_cast<const float4*>(s)[j];
        bf16x4 o = { (bf16)v.x, (bf16)v.y, (bf16)v.z, (bf16)v.w };
        if (img) {
            int e = j * 4, col = e >> 9, kc = e & 511, kk = kc >> 5, k = kc & 31;
            int off = kk * 16384 + col * 32 + (k ^ swz(col));
            *reinterpret_cast<bf16x4*>(d + off) = o;
        } else {
            reinterpret_cast<bf16x4*>(d)[j] = o;
        }
    }
}

// ---------------- generic GEMM: C[M,N] = A[M,K] * B[N,K]^T + bias[N] ----------------
__global__ __launch_bounds__(256) void gemm_bias(
    const bf16* __restrict__ A, const bf16* __restrict__ B,
    const float* __restrict__ bias, float* __restrict__ C,
    int M, int N, int K) {
    __shared__ bf16 At[64][40];
    __shared__ bf16 Bt[64][40];
    const int tid = threadIdx.x;
    const int m0 = blockIdx.y * 64, n0 = blockIdx.x * 64;
    const int wid = tid >> 6, lane = tid & 63, hi = lane >> 4, lo = lane & 15;
    const int srow = tid >> 2, sseg = tid & 3;
    f32x4 acc[4] = {};

    for (int kk = 0; kk < K; kk += 32) {
        bf16x8 av = *reinterpret_cast<const bf16x8*>(A + (size_t)(m0 + srow) * K + kk + sseg * 8);
        bf16x8 bv = *reinterpret_cast<const bf16x8*>(B + (size_t)(n0 + srow) * K + kk + sseg * 8);
        __syncthreads();
        *reinterpret_cast<bf16x8*>(&At[srow][sseg * 8]) = av;
        *reinterpret_cast<bf16x8*>(&Bt[srow][sseg * 8]) = bv;
        __syncthreads();
        bf16x8 a = *reinterpret_cast<const bf16x8*>(&At[wid * 16 + lo][hi * 8]);
#pragma unroll
        for (int nt = 0; nt < 4; ++nt) {
            bf16x8 b = *reinterpret_cast<const bf16x8*>(&Bt[nt * 16 + lo][hi * 8]);
            acc[nt] = __builtin_amdgcn_mfma_f32_16x16x32_bf16(a, b, acc[nt], 0, 0, 0);
        }
    }
#pragma unroll
    for (int nt = 0; nt < 4; ++nt) {
        int n = n0 + nt * 16 + lo;
        float bv = bias[n];
#pragma unroll
        for (int r = 0; r < 4; ++r) {
            int m = m0 + wid * 16 + hi * 4 + r;
            C[(size_t)m * N + n] = acc[nt][r] + bv;
        }
    }
}

// ---------------- fused emit kernel (v3: K-stepped, double-buffered LDS) ----------------
// emit[m] = sum_n tanh((feats W^T)[m,n] + h_[b(m),n]) * w_score[n]
// 64 m-rows/block, 8 waves x 64 n-cols, K-step 32, A reg-staged f32->bf16, B DMA'd.
__global__ __launch_bounds__(512, 4) void emit_kernel(
    const float* __restrict__ feats, const bf16* __restrict__ Wimg,
    const float* __restrict__ hbuf, const float* __restrict__ wscore,
    float* __restrict__ emit_out) {
    __shared__ bf16 Btile[2][16384];   // 64 KB: [512 col][32 k] swizzled
    __shared__ bf16 Atile[2][2048];    // 8 KB:  [64 row][32 k] swizzled
    __shared__ float ew[512];
    const int tid = threadIdx.x;
    const int m0 = blockIdx.x * 64;
    const int wid = tid >> 6, lane = tid & 63, hi = lane >> 4, lo = lane & 15;

    // A staging coords: thread -> (row, 4-float segment)
    const int arow = tid >> 3, akq = tid & 7;
    const int aoff = arow * 32 + ((akq * 4) ^ swz(arow));
    const float* asrc = feats + (size_t)(m0 + arow) * NIN + akq * 4;

    // prologue: stage k-step 0
#pragma unroll
    for (int r = 0; r < 4; ++r)
        gload_lds16(Wimg + r * 4096 + wid * 512 + lane * 8,
                    &Btile[0][r * 4096 + wid * 512]);
    {
        float4 fa = *reinterpret_cast<const float4*>(asrc);
        bf16x4 o = { (bf16)fa.x, (bf16)fa.y, (bf16)fa.z, (bf16)fa.w };
        *reinterpret_cast<bf16x4*>(&Atile[0][aoff]) = o;
    }
    __syncthreads();

    f32x4 acc[4][4] = {};   // [nt][st]
    float4 fa;
    for (int kk = 0; kk < 16; ++kk) {
        const int cur = kk & 1, nxt = cur ^ 1;
        // issue next-step loads first (A to regs, B via DMA) — latency hides under MFMA
        if (kk < 15) {
            fa = *reinterpret_cast<const float4*>(asrc + (kk + 1) * 32);
#pragma unroll
            for (int r = 0; r < 4; ++r)
                gload_lds16(Wimg + (kk + 1) * 16384 + r * 4096 + wid * 512 + lane * 8,
                            &Btile[nxt][r * 4096 + wid * 512]);
        }

        bf16x8 a[4], b[4];
#pragma unroll
        for (int st = 0; st < 4; ++st) {
            int row = st * 16 + lo;
            a[st] = *reinterpret_cast<const bf16x8*>(
                &Atile[cur][row * 32 + ((hi * 8) ^ swz(row))]);
        }
#pragma unroll
        for (int nt = 0; nt < 4; ++nt) {
            int col = wid * 64 + nt * 16 + lo;
            b[nt] = *reinterpret_cast<const bf16x8*>(
                &Btile[cur][col * 32 + ((hi * 8) ^ swz(col))]);
        }
#pragma unroll
        for (int nt = 0; nt < 4; ++nt)
#pragma unroll
            for (int st = 0; st < 4; ++st)
                acc[nt][st] = __builtin_amdgcn_mfma_f32_16x16x32_bf16(a[st], b[nt], acc[nt][st], 0, 0, 0);

        if (kk < 15) {
            bf16x4 o = { (bf16)fa.x, (bf16)fa.y, (bf16)fa.z, (bf16)fa.w };
            *reinterpret_cast<bf16x4*>(&Atile[nxt][aoff]) = o;
        }
        __syncthreads();
    }

    // epilogue: add h_, tanh, dot with w_score
    float ep[4][4] = {};                 // [st][r]
    const int bbase = m0 & (B_DIM - 1);
    const int n0 = wid * 64;
#pragma unroll
    for (int nt = 0; nt < 4; ++nt) {
        int n = n0 + nt * 16 + lo;
        float wsn = wscore[n];
#pragma unroll
        for (int st = 0; st < 4; ++st) {
#pragma unroll
            for (int r = 0; r < 4; ++r) {
                int b = bbase + st * 16 + hi * 4 + r;
                float x = acc[nt][st][r] + hbuf[(size_t)b * NH + n];
                ep[st][r] += fast_tanh(x) * wsn;
            }
        }
    }
#pragma unroll
    for (int st = 0; st < 4; ++st)
#pragma unroll
        for (int r = 0; r < 4; ++r)
#pragma unroll
            for (int off = 1; off < 16; off <<= 1)
                ep[st][r] += __shfl_xor(ep[st][r], off, 64);

    if (lo == 0) {
#pragma unroll
        for (int st = 0; st < 4; ++st)
#pragma unroll
            for (int r = 0; r < 4; ++r)
                ew[wid * 64 + st * 16 + hi * 4 + r] = ep[st][r];
    }
    __syncthreads();
    if (tid < 64) {
        float s = 0.0f;
#pragma unroll
        for (int ww = 0; ww < 8; ++ww) s += ew[ww * 64 + tid];
        emit_out[m0 + tid] = s;
    }
}

// ---------------- softmax over T (per column b) ----------------
__global__ __launch_bounds__(256) void softmax_t(
    const float* __restrict__ emit, float* __restrict__ alpha, float* __restrict__ out_alpha) {
    int b = blockIdx.x, t = threadIdx.x;
    int wv = t >> 6, ln = t & 63;
    float e = emit[(size_t)t * B_DIM + b];
    float m = e;
#pragma unroll
    for (int off = 32; off; off >>= 1) m = fmaxf(m, __shfl_xor(m, off, 64));
    __shared__ float red[4], red2[4];
    if (ln == 0) red[wv] = m;
    __syncthreads();
    m = fmaxf(fmaxf(red[0], red[1]), fmaxf(red[2], red[3]));
    float p = __expf(e - m);
    float s = p;
#pragma unroll
    for (int off = 32; off; off >>= 1) s += __shfl_xor(s, off, 64);
    if (ln == 0) red2[wv] = s;
    __syncthreads();
    float inv = __builtin_amdgcn_rcpf(red2[0] + red2[1] + red2[2] + red2[3]);
    float a = p * inv;
    alpha[(size_t)t * B_DIM + b] = a;
    out_alpha[(size_t)t * B_DIM + b] = a;
}

// ---------------- context + build_x fused (reads f32 feats, L3-resident) ----------------
__global__ __launch_bounds__(256) void ctx_kernel(
    const float* __restrict__ feats, const float* __restrict__ alpha,
    const float* __restrict__ emb, bf16* __restrict__ x) {
    int b = blockIdx.x;
    __shared__ float al[T_DIM];
    __shared__ float red[4][512];
    int tid = threadIdx.x;
    al[tid] = alpha[(size_t)tid * B_DIM + b];
    __syncthreads();
    int c8 = tid & 63, tq = tid >> 6;
    float acc[8] = {};
    for (int t = tq * 64; t < tq * 64 + 64; ++t) {
        const float* src = feats + ((size_t)(t * B_DIM + b)) * NIN + c8 * 8;
        float4 v0 = *reinterpret_cast<const float4*>(src);
        float4 v1 = *reinterpret_cast<const float4*>(src + 4);
        float a = al[t];
        acc[0] += a * v0.x; acc[1] += a * v0.y; acc[2] += a * v0.z; acc[3] += a * v0.w;
        acc[4] += a * v1.x; acc[5] += a * v1.y; acc[6] += a * v1.z; acc[7] += a * v1.w;
    }
#pragma unroll
    for (int j = 0; j < 8; ++j) red[tq][c8 * 8 + j] = acc[j];
    __syncthreads();
#pragma unroll
    for (int k = 0; k < 2; ++k) {
        int c = tid * 2 + k;
        float s = red[0][c] + red[1][c] + red[2][c] + red[3][c];
        x[(size_t)b * NX + c] = (bf16)s;
    }
    x[(size_t)b * NX + NIN + tid] = (bf16)emb[(size_t)b * NEMB + tid];
}

// ---------------- GRU gates ----------------
__global__ __launch_bounds__(256) void gru_kernel(
    const float* __restrict__ gi, const float* __restrict__ gh,
    const float* __restrict__ h, float* __restrict__ out) {
    int idx = blockIdx.x * 256 + threadIdx.x;
    int b = idx >> 9, j = idx & 511;
    const float* gib = gi + (size_t)b * NG;
    const float* ghb = gh + (size_t)b * NG;
    float r = fast_sigmoid(gib[j] + ghb[j]);
    float z = fast_sigmoid(gib[NH + j] + ghb[NH + j]);
    float n = fast_tanh(gib[2 * NH + j] + r * ghb[2 * NH + j]);
    out[idx] = (1.0f - z) * n + z * h[idx];
}

extern "C" void kernel_launch(void* const* d_in, const int* in_sizes, int n_in,
                              void* d_out, int out_size, void* d_ws, size_t ws_size,
                              hipStream_t stream) {
    const float* feats = (const float*)d_in[0];
    const float* h     = (const float*)d_in[1];
    const float* emb   = (const float*)d_in[2];
    const float* w_i2h = (const float*)d_in[3];
    const float* w_h2h = (const float*)d_in[4];
    const float* b_h2h = (const float*)d_in[5];
    const float* w_sc  = (const float*)d_in[6];
    const float* w_ih  = (const float*)d_in[7];
    const float* w_hh  = (const float*)d_in[8];
    const float* b_ih  = (const float*)d_in[9];
    const float* b_hh  = (const float*)d_in[10];
    float* out = (float*)d_out;

    char* ws = (char*)d_ws;
    bf16*  Wimg    = (bf16*)(ws);                 // 524288 (swizzled K-step image)
    bf16*  w_h2h_b = (bf16*)(ws + 524288);        // 524288
    bf16*  w_ih_b  = (bf16*)(ws + 1048576);       // 2359296
    bf16*  w_hh_b  = (bf16*)(ws + 3407872);       // 1572864
    bf16*  h_b     = (bf16*)(ws + 4980736);       // 262144
    bf16*  x_b     = (bf16*)(ws + 5242880);       // 393216
    float* hbuf    = (float*)(ws + 5636096);      // 524288
    float* emit    = (float*)(ws + 6160384);      // 262144
    float* alpha   = (float*)(ws + 6422528);      // 262144
    float* gi      = (float*)(ws + 6684672);      // 1572864
    float* gh      = (float*)(ws + 8257536);      // 1572864  -> total 9830400

    // 1) weight/h conversions (w_i2h -> swizzled Wimg)
    cvt_weights<<<1024, 256, 0, stream>>>(w_i2h, w_h2h, w_ih, w_hh, h,
                                          Wimg, w_h2h_b, w_ih_b, w_hh_b, h_b);

    // 2) h_ = h @ w_h2h^T + b_h2h
    gemm_bias<<<dim3(8, 4), 256, 0, stream>>>(h_b, w_h2h_b, b_h2h, hbuf, 256, NH, NH);

    // 3) fused emit (reads f32 feats directly)
    emit_kernel<<<1024, 512, 0, stream>>>(feats, Wimg, hbuf, w_sc, emit);

    // 4) alpha = softmax_T(emit); also output 1
    softmax_t<<<256, 256, 0, stream>>>(emit, alpha, out + 131072);

    // 5) context + x build (fused, f32 feats from L3)
    ctx_kernel<<<256, 256, 0, stream>>>(feats, alpha, emb, x_b);

    // 6) gi / gh GEMMs
    gemm_bias<<<dim3(24, 4), 256, 0, stream>>>(x_b, w_ih_b, b_ih, gi, 256, NG, NX);
    gemm_bias<<<dim3(24, 4), 256, 0, stream>>>(h_b, w_hh_b, b_hh, gh, 256, NG, NH);

    // 7) GRU -> nh (output 0)
    gru_kernel<<<512, 256, 0, stream>>>(gi, gh, h, out);
}